// Round 8
// baseline (563.023 us; speedup 1.0000x reference)
//
#include <hip/hip_runtime.h>

// ---------------------------------------------------------------------------
// Dims: E=768 P=256 K=32 V=32 H=128 NE=8  B=16 M=4 T=512
// rows = 32768, sequences = 64.  All inputs f32; output f32.
// R12/R13: (1) k_proc tile 128x64 (32 MFMA per barrier pair, was 16).
// (2) k_hid epilogue: W2 transposed in LDS [8][196] -> b128 reads (144 LDS
// instr vs 384 scalar). (3) k_gru micro: gout store moved post-barrier
// (fills ds_read shadow), branchless 1-write/lane h writeback, uvw prefetch.
// k_gru structure otherwise R9 (latency-bound at 64 CUs; TLP refuted R10).
// (R13 = resubmission of R12 after infra failure; no functional change.)
// ---------------------------------------------------------------------------

typedef __attribute__((ext_vector_type(8))) short short8;
typedef __attribute__((ext_vector_type(4))) float f32x4;

__device__ __forceinline__ float bf2f(unsigned short u) {
    return __uint_as_float(((unsigned int)u) << 16);
}
__device__ __forceinline__ unsigned short f2bf(float f) {  // RNE
    unsigned int x = __float_as_uint(f);
    return (unsigned short)((x + 0x7FFFu + ((x >> 16) & 1u)) >> 16);
}
__device__ __forceinline__ float sigm(float x) { return 1.0f / (1.0f + __expf(-x)); }
__device__ __forceinline__ float tanh_fast(float x) {
    x = fminf(fmaxf(x, -15.0f), 15.0f);
    float e = __expf(-2.0f * x);
    return (1.0f - e) / (1.0f + e);
}
// lane^1 pair-sum via DPP quad_perm [1,0,3,2] (ctrl 0xB1) — pure VALU pipe.
__device__ __forceinline__ float dpp_xor1_add(float v) {
    int o = __builtin_amdgcn_update_dpp(0, __float_as_int(v), 0xB1, 0xF, 0xF, true);
    return v + __int_as_float(o);
}
// select c[sel] for sel in 0..3 (3 cndmask)
__device__ __forceinline__ float sel4(f32x4 c, int sel) {
    float t0 = (sel & 1) ? c[1] : c[0];
    float t1 = (sel & 1) ? c[3] : c[2];
    return (sel & 2) ? t1 : t0;
}

// const block layout (floats): wA@0 wB@256 wC@512 | cA,cB,cC@768 |
// wu@800 wA2@1184 wB2@1568 cc@1952  (end 2336)
#define CST_SC   768
#define CST_WU   800
#define CST_WA2  1184
#define CST_WB2  1568
#define CST_CC   1952

__global__ void k_paint(float* out, float val, int nmax) {
    int i = blockIdx.x * blockDim.x + threadIdx.x;
    if (i < nmax) out[i] = val;
}

// ---------------------------------------------------------------------------
// k_prep: weight fusions.  <<<1, 512>>>
// ---------------------------------------------------------------------------
__global__ void k_prep(const float* __restrict__ Wq,
                       const float* __restrict__ bq,
                       const float* __restrict__ Wk,
                       const float* __restrict__ bk,
                       const float* __restrict__ Wv,
                       const float* __restrict__ bv,
                       const float* __restrict__ Wih,
                       const float* __restrict__ bih,
                       float* __restrict__ cst)
{
    const int t = threadIdx.x;
    if (t < 256) {
        float a = 0.f, b = 0.f, c = 0.f;
        for (int k = 0; k < 32; ++k) {
            float w = Wq[t * 32 + k];
            a = fmaf(w, Wk[k], a);
            b = fmaf(w, Wk[32 + k], b);
            c = fmaf(w, bk[k], c);
        }
        cst[t] = a; cst[256 + t] = b; cst[512 + t] = c;
    }
    if (t == 0) {
        float ca = 0.f, cb = 0.f, cc = 0.f;
        for (int k = 0; k < 32; ++k) {
            float bqk = bq[k];
            ca = fmaf(bqk, Wk[k], ca);
            cb = fmaf(bqk, Wk[32 + k], cb);
            cc = fmaf(bqk, bk[k], cc);
        }
        cst[CST_SC + 0] = ca; cst[CST_SC + 1] = cb; cst[CST_SC + 2] = cc;
    }
    if (t < 384) {
        cst[CST_WU + t] = Wih[t * 33];
        float a2 = 0.f, b2 = 0.f, c2 = bih[t];
        for (int v = 0; v < 32; ++v) {
            float w = Wih[t * 33 + 1 + v];
            a2 = fmaf(w, Wv[v], a2);
            b2 = fmaf(w, Wv[32 + v], b2);
            c2 = fmaf(w, bv[v], c2);
        }
        cst[CST_WA2 + t] = a2; cst[CST_WB2 + t] = b2; cst[CST_CC + t] = c2;
    }
}

// ---------------------------------------------------------------------------
// k_proc (R12): proc = relu(emb @ W_tp + b_tp) -> bf16. MFMA 16x16x32.
// Tile 128x64, BK=32, block 256 (4 waves, 2x2 grid of 64x32), grid (4,256).
// 32 MFMA per staging+2-barrier pair per block (2x the 64x64 tile).
// ---------------------------------------------------------------------------
__global__ __launch_bounds__(256) void k_proc(
    const float* __restrict__ A,     // [32768,768] f32
    const float* __restrict__ Bw,    // [768,256]  f32
    const float* __restrict__ bias,  // [256] f32
    unsigned short* __restrict__ C)  // [32768,256] bf16
{
    __shared__ unsigned short A_s[128 * 40];  // [row][k] stride 40
    __shared__ unsigned short B_s[64 * 40];   // [col][k] stride 40 (transposed)
    const int t = threadIdx.x;
    const int row0 = blockIdx.y * 128;
    const int col0 = blockIdx.x * 64;
    const int lane = t & 63, wave = t >> 6;
    const int wr = wave >> 1, wc = wave & 1;      // 2x2 wave grid of 64x32
    const int quad = lane >> 4, l16 = lane & 15;

    f32x4 acc[4][2] = {};

    for (int k0 = 0; k0 < 768; k0 += 32) {
        {   // A tile: 128 rows x 32 k; thread: row=t>>1, 16 k each
            const int r = t >> 1, kq = (t & 1) * 16;
            const float* src = A + (size_t)(row0 + r) * 768 + k0 + kq;
            float4 v0 = *(const float4*)(src);
            float4 v1 = *(const float4*)(src + 4);
            float4 v2 = *(const float4*)(src + 8);
            float4 v3 = *(const float4*)(src + 12);
            short8 s0, s1;
            s0[0] = f2bf(v0.x); s0[1] = f2bf(v0.y); s0[2] = f2bf(v0.z); s0[3] = f2bf(v0.w);
            s0[4] = f2bf(v1.x); s0[5] = f2bf(v1.y); s0[6] = f2bf(v1.z); s0[7] = f2bf(v1.w);
            s1[0] = f2bf(v2.x); s1[1] = f2bf(v2.y); s1[2] = f2bf(v2.z); s1[3] = f2bf(v2.w);
            s1[4] = f2bf(v3.x); s1[5] = f2bf(v3.y); s1[6] = f2bf(v3.z); s1[7] = f2bf(v3.w);
            *(short8*)(A_s + r * 40 + kq) = s0;
            *(short8*)(A_s + r * 40 + kq + 8) = s1;
        }
        {   // B tile: 32 k x 64 cols, transposed into [col][k]
            const int k = t >> 3, nq = (t & 7) * 8;
            const float* src = Bw + (size_t)(k0 + k) * 256 + col0 + nq;
            float4 v0 = *(const float4*)(src);
            float4 v1 = *(const float4*)(src + 4);
            B_s[(nq + 0) * 40 + k] = f2bf(v0.x);
            B_s[(nq + 1) * 40 + k] = f2bf(v0.y);
            B_s[(nq + 2) * 40 + k] = f2bf(v0.z);
            B_s[(nq + 3) * 40 + k] = f2bf(v0.w);
            B_s[(nq + 4) * 40 + k] = f2bf(v1.x);
            B_s[(nq + 5) * 40 + k] = f2bf(v1.y);
            B_s[(nq + 6) * 40 + k] = f2bf(v1.z);
            B_s[(nq + 7) * 40 + k] = f2bf(v1.w);
        }
        __syncthreads();
        short8 af[4], bf[2];
        #pragma unroll
        for (int im = 0; im < 4; ++im)
            af[im] = *(const short8*)(A_s + (wr * 64 + im * 16 + l16) * 40 + quad * 8);
        #pragma unroll
        for (int in = 0; in < 2; ++in)
            bf[in] = *(const short8*)(B_s + (wc * 32 + in * 16 + l16) * 40 + quad * 8);
        #pragma unroll
        for (int im = 0; im < 4; ++im)
            #pragma unroll
            for (int in = 0; in < 2; ++in)
                acc[im][in] = __builtin_amdgcn_mfma_f32_16x16x32_bf16(
                    af[im], bf[in], acc[im][in], 0, 0, 0);
        __syncthreads();
    }
    float bias_v[2];
    #pragma unroll
    for (int in = 0; in < 2; ++in) bias_v[in] = bias[col0 + wc * 32 + in * 16 + l16];
    #pragma unroll
    for (int im = 0; im < 4; ++im)
        #pragma unroll
        for (int in = 0; in < 2; ++in) {
            const int c_g = col0 + wc * 32 + in * 16 + l16;
            #pragma unroll
            for (int reg = 0; reg < 4; ++reg) {
                const int r_g = row0 + wr * 64 + im * 16 + quad * 4 + reg;
                float v = fmaxf(acc[im][in][reg] + bias_v[in], 0.f);
                C[(size_t)r_g * 256 + c_g] = f2bf(v);
            }
        }
}

// ---------------------------------------------------------------------------
// k_attn: one WAVE per row; rank-1 attention reduced to (wr, ws) per row.
// ---------------------------------------------------------------------------
__global__ __launch_bounds__(256) void k_attn(
    const unsigned short* __restrict__ proc,  // bf16 internal
    const float* __restrict__ R,              // [16,4,4,512] f32
    const float* __restrict__ S,
    const float* __restrict__ cst,
    float* __restrict__ wrws)                 // [32768,2] f32
{
    __shared__ float wv_s[768];
    const int tid = threadIdx.x;
    for (int i = tid; i < 768; i += 256) wv_s[i] = cst[i];
    __syncthreads();

    const int lane = tid & 63, wave = tid >> 6;
    const int row = blockIdx.x * 4 + wave;
    const int t = row & 511, m = (row >> 9) & 3, b = row >> 11;
    const int p0 = lane * 4;

    ushort4 u = *(const ushort4*)(proc + (size_t)row * 256 + p0);
    float p0f = bf2f(u.x), p1f = bf2f(u.y), p2f = bf2f(u.z), p3f = bf2f(u.w);
    float dA = 0.f, dB = 0.f, dC = 0.f;
    dA = fmaf(p0f, wv_s[p0 + 0], dA); dB = fmaf(p0f, wv_s[256 + p0 + 0], dB); dC = fmaf(p0f, wv_s[512 + p0 + 0], dC);
    dA = fmaf(p1f, wv_s[p0 + 1], dA); dB = fmaf(p1f, wv_s[256 + p0 + 1], dB); dC = fmaf(p1f, wv_s[512 + p0 + 1], dC);
    dA = fmaf(p2f, wv_s[p0 + 2], dA); dB = fmaf(p2f, wv_s[256 + p0 + 2], dB); dC = fmaf(p2f, wv_s[512 + p0 + 2], dC);
    dA = fmaf(p3f, wv_s[p0 + 3], dA); dB = fmaf(p3f, wv_s[256 + p0 + 3], dB); dC = fmaf(p3f, wv_s[512 + p0 + 3], dC);
    #pragma unroll
    for (int mm = 1; mm < 64; mm <<= 1) {
        dA += __shfl_xor(dA, mm, 64);
        dB += __shfl_xor(dB, mm, 64);
        dC += __shfl_xor(dC, mm, 64);
    }
    if (lane == 0) {
        dA += cst[CST_SC + 0]; dB += cst[CST_SC + 1]; dC += cst[CST_SC + 2];
        const float scale = 0.17677669529663687f;  // 1/sqrt(32)
        float rr[4], ss[4], sc[4], mx = -1e30f;
        #pragma unroll
        for (int j = 0; j < 4; ++j) {
            const size_t idx = ((size_t)(b * 16 + m * 4 + j)) * 512 + t;
            rr[j] = R[idx]; ss[j] = S[idx];
            float v = (rr[j] * dA + ss[j] * dB + dC) * scale;
            if (j == m) v = -1e9f;
            sc[j] = v; mx = fmaxf(mx, v);
        }
        float w[4], se = 0.f;
        #pragma unroll
        for (int j = 0; j < 4; ++j) { w[j] = __expf(sc[j] - mx); se += w[j]; }
        const float inv = 1.0f / se;
        float wr = 0.f, wss = 0.f;
        #pragma unroll
        for (int j = 0; j < 4; ++j) { wr += w[j] * rr[j]; wss += w[j] * ss[j]; }
        float2 o; o.x = wr * inv; o.y = wss * inv;
        ((float2*)wrws)[row] = o;
    }
}

// ---------------------------------------------------------------------------
// k_gru (R12): R9 structure + post-barrier gout store (fills ds_read
// shadow), branchless 1-write/lane h writeback (par0->hi, par1->lo),
// uvw[t+1] register prefetch. 64 blocks x 256 threads (4 waves); wave w
// owns h[32w..32w+32); eg = 32w + 16hh + 4quad + sel; 24 MFMA/wave/step.
// ---------------------------------------------------------------------------
__global__ __launch_bounds__(256) void k_gru(
    const float* __restrict__ wrws,
    const float* __restrict__ U,       // [32768] f32
    const float* __restrict__ Whh,     // [384,128] f32
    const float* __restrict__ bhh,     // [384] f32
    const float* __restrict__ cst,
    unsigned short* __restrict__ gout) // [32768,128] bf16
{
    __shared__ unsigned short hbuf[2][2][144];  // [buf][hi/lo][128 + 16 pad] bf16
    __shared__ float4 uvw_s[512];               // {u, wr, ws, 0} per t

    const int tid  = threadIdx.x;
    const int lane = tid & 63, w = tid >> 6;      // 4 waves
    const int l16  = lane & 15, quad = lane >> 4;
    const int n    = blockIdx.x;
    const int par  = l16 & 1;                     // B col parity: even=hi, odd=lo
    const int sel  = (l16 >> 1) & 3;              // C-fragment reg select
    const int hh   = (l16 >> 3) & 1;              // tile half select
    const int eg   = 32 * w + 16 * hh + quad * 4 + sel;  // this lane's h element

    // ---- A fragments: 6 row-tiles (3 gates x 2 halves), bf16 ----
    short8 afr[3][2][4];
    #pragma unroll
    for (int g3 = 0; g3 < 3; ++g3)
        #pragma unroll
        for (int h2 = 0; h2 < 2; ++h2) {
            const int row = g3 * 128 + 32 * w + 16 * h2 + l16;
            const float* rp = Whh + (size_t)row * 128 + quad * 8;
            #pragma unroll
            for (int kf = 0; kf < 4; ++kf) {
                float4 v0 = *(const float4*)(rp + kf * 32);
                float4 v1 = *(const float4*)(rp + kf * 32 + 4);
                short8 s;
                s[0] = f2bf(v0.x); s[1] = f2bf(v0.y); s[2] = f2bf(v0.z); s[3] = f2bf(v0.w);
                s[4] = f2bf(v1.x); s[5] = f2bf(v1.y); s[6] = f2bf(v1.z); s[7] = f2bf(v1.w);
                afr[g3][h2][kf] = s;
            }
        }

    // ---- per-lane gi constants for element eg (bhh folded for r,z) ----
    const float wu_r = cst[CST_WU  + eg], wu_z = cst[CST_WU  + 128 + eg], wu_n = cst[CST_WU  + 256 + eg];
    const float wa_r = cst[CST_WA2 + eg], wa_z = cst[CST_WA2 + 128 + eg], wa_n = cst[CST_WA2 + 256 + eg];
    const float wb_r = cst[CST_WB2 + eg], wb_z = cst[CST_WB2 + 128 + eg], wb_n = cst[CST_WB2 + 256 + eg];
    const float cc_r = cst[CST_CC  + eg] + bhh[eg];
    const float cc_z = cst[CST_CC  + 128 + eg] + bhh[128 + eg];
    const float cc_n = cst[CST_CC  + 256 + eg];
    const float bh_n = bhh[256 + eg];

    for (int i = tid; i < 512; i += 256) {   // per-t scalars, packed float4
        float u = U[(size_t)n * 512 + i];
        float2 w2 = ((const float2*)wrws)[(size_t)n * 512 + i];
        float4 p; p.x = u; p.y = w2.x; p.z = w2.y; p.w = 0.f;
        uvw_s[i] = p;
    }
    for (int i = tid; i < 288; i += 256) ((unsigned int*)hbuf)[i] = 0u;  // zero h bufs
    __syncthreads();

    float h_old = 0.f;
    unsigned short prev_hi = 0;
    unsigned short* gp = gout + (size_t)n * 512 * 128 + eg;
    float4 uvw = uvw_s[0];
    const f32x4 ZZ = {0.f, 0.f, 0.f, 0.f};

    #pragma unroll 2
    for (int t = 0; t < 512; ++t) {
        const int cur = t & 1, nxt = cur ^ 1;

        // previous step's gout store — issued in the post-barrier ds_read shadow
        if (t && par == 0) gp[(size_t)(t - 1) * 128] = prev_hi;

        // B fragments: h broadcast; col parity picks hi/lo plane
        const unsigned short* hb = &hbuf[cur][par][0];
        short8 bfr[4];
        #pragma unroll
        for (int kf = 0; kf < 4; ++kf)
            bfr[kf] = *(const short8*)(hb + kf * 32 + quad * 8);

        f32x4 c[6] = {ZZ, ZZ, ZZ, ZZ, ZZ, ZZ};   // c[2g+hh]: 6 chains of 4
        #pragma unroll
        for (int kf = 0; kf < 4; ++kf)
            #pragma unroll
            for (int j = 0; j < 6; ++j)
                c[j] = __builtin_amdgcn_mfma_f32_16x16x32_bf16(
                    afr[j >> 1][j & 1][kf], bfr[kf], c[j], 0, 0, 0);

        // gate g of eg = row (quad*4+sel), col l16 of tile c[2g+hh];
        // DPP xor-1 adds hi(par=0) + lo(par=1) partial products.
        float gh[3];
        #pragma unroll
        for (int g3 = 0; g3 < 3; ++g3) {
            const float v0 = sel4(c[2 * g3 + 0], sel);
            const float v1 = sel4(c[2 * g3 + 1], sel);
            gh[g3] = dpp_xor1_add(hh ? v1 : v0);
        }

        const float gir = fmaf(uvw.z, wb_r, fmaf(uvw.y, wa_r, fmaf(uvw.x, wu_r, cc_r)));
        const float giz = fmaf(uvw.z, wb_z, fmaf(uvw.y, wa_z, fmaf(uvw.x, wu_z, cc_z)));
        const float gin = fmaf(uvw.z, wb_n, fmaf(uvw.y, wa_n, fmaf(uvw.x, wu_n, cc_n)));
        const float r  = sigm(gir + gh[0]);
        const float z  = sigm(giz + gh[1]);
        const float nn = tanh_fast(fmaf(r, gh[2] + bh_n, gin));
        const float hn = fmaf(z, h_old - nn, nn);
        h_old = hn;

        const float4 uvw_n = uvw_s[(t + 1) & 511];   // prefetch next (pre-barrier)

        // branchless h writeback: par0 lane writes hi plane, par1 writes lo
        const unsigned short hi16 = f2bf(hn);
        const unsigned short wv = par ? f2bf(hn - bf2f(hi16)) : hi16;
        hbuf[nxt][par][eg] = wv;
        prev_hi = hi16;

        asm volatile("s_waitcnt lgkmcnt(0)" ::: "memory");
        __builtin_amdgcn_s_barrier();
        asm volatile("" ::: "memory");
        __builtin_amdgcn_sched_barrier(0x7);  // ALU may cross; DS/VMEM/MFMA pinned
        uvw = uvw_n;
    }
    if (par == 0) gp[(size_t)511 * 128] = prev_hi;
}

// ---------------------------------------------------------------------------
// k_hid (R12): hidden = relu([proc|gout]@W1 + b1) via MFMA (W1 bf16 hi+lo),
// logits = hidden@W2 + b2 with W2 TRANSPOSED in LDS [8][196] -> b128 reads.
// ---------------------------------------------------------------------------
__global__ __launch_bounds__(256) void k_hid(
    const unsigned short* __restrict__ proc,  // bf16 [32768,256]
    const unsigned short* __restrict__ gout,  // bf16 [32768,128]
    const float* __restrict__ W1,   // [384,192] f32
    const float* __restrict__ b1,   // [192] f32
    const float* __restrict__ W2,   // [192,8] f32
    const float* __restrict__ b2,   // [8] f32
    float* __restrict__ out)        // [32768,8] f32
{
    // LDS: K-loop  As[64][40] bf16 @0 (5120) | Bh[192][40] @5120 (15360) |
    //              Bl[192][40] @20480 (15360)            (K-loop total 35840)
    //      Epilog  Hs[64][196] f32 @0 (50176)  (reuses K-loop region)
    //      Always  W2t[8][196] f32 @50176 (6272) | b2s[8] @56448 (32)
    __shared__ __align__(16) unsigned char smem[56480];
    unsigned short* As = (unsigned short*)smem;            // stride 40
    unsigned short* Bh = (unsigned short*)(smem + 5120);   // stride 40
    unsigned short* Bl = (unsigned short*)(smem + 20480);  // stride 40
    float* Hs  = (float*)smem;                             // stride 196
    float* W2t = (float*)(smem + 50176);                   // [8][196]
    float* b2s = (float*)(smem + 56448);

    const int tid = threadIdx.x;
    const int row0 = blockIdx.x * 64;
    const int lane = tid & 63, w = tid >> 6;
    const int l16 = lane & 15, quad = lane >> 4;

    for (int i = tid; i < 1536; i += 256) {   // W2 [192,8] -> W2t [8][196]
        const int c = i >> 3, e = i & 7;
        W2t[e * 196 + c] = W2[i];
    }
    if (tid < 8) b2s[tid] = b2[tid];

    // staging maps: A: 8 bf16/thread; B: 2 k-rows x 12 cols (stride-16)/thread
    const int ar = tid >> 2, akq = (tid & 3) * 8;
    const int bk2 = (tid >> 4) * 2, bc0 = tid & 15;

    f32x4 acc[4][3] = {};

    for (int k0 = 0; k0 < 384; k0 += 32) {
        __syncthreads();   // previous iter's fragment reads complete
        {   // A tile: 64 rows x 32 k (bf16 direct copy from proc/gout)
            const int kk = k0 + akq;
            short8 v;
            if (kk < 256) v = *(const short8*)(proc + (size_t)(row0 + ar) * 256 + kk);
            else          v = *(const short8*)(gout + (size_t)(row0 + ar) * 128 + (kk - 256));
            *(short8*)(As + ar * 40 + akq) = v;
        }
        {   // B tile: W1[k0..k0+32][0..192] f32 -> [col][k] bf16 hi+lo planes
            const float* wrow0 = W1 + (size_t)(k0 + bk2) * 192;
            const float* wrow1 = wrow0 + 192;
            #pragma unroll
            for (int j = 0; j < 12; ++j) {
                const int c = bc0 + 16 * j;
                const float f0 = wrow0[c], f1 = wrow1[c];
                const unsigned short h0 = f2bf(f0), h1 = f2bf(f1);
                const unsigned short s0 = f2bf(f0 - bf2f(h0));
                const unsigned short s1 = f2bf(f1 - bf2f(h1));
                *(unsigned int*)(Bh + c * 40 + bk2) = (unsigned int)h0 | ((unsigned int)h1 << 16);
                *(unsigned int*)(Bl + c * 40 + bk2) = (unsigned int)s0 | ((unsigned int)s1 << 16);
            }
        }
        __syncthreads();
        short8 af[4], bh[3], bl[3];
        #pragma unroll
        for (int m = 0; m < 4; ++m)
            af[m] = *(const short8*)(As + (m * 16 + l16) * 40 + quad * 8);
        #pragma unroll
        for (int nn = 0; nn < 3; ++nn) {
            const int col = w * 48 + nn * 16 + l16;
            bh[nn] = *(const short8*)(Bh + col * 40 + quad * 8);
            bl[nn] = *(const short8*)(Bl + col * 40 + quad * 8);
        }
        #pragma unroll
        for (int m = 0; m < 4; ++m)
            #pragma unroll
            for (int nn = 0; nn < 3; ++nn) {
                acc[m][nn] = __builtin_amdgcn_mfma_f32_16x16x32_bf16(af[m], bh[nn], acc[m][nn], 0, 0, 0);
                acc[m][nn] = __builtin_amdgcn_mfma_f32_16x16x32_bf16(af[m], bl[nn], acc[m][nn], 0, 0, 0);
            }
    }
    __syncthreads();   // done with K-loop LDS before Hs overwrite
    {
        float b1v[3];
        #pragma unroll
        for (int nn = 0; nn < 3; ++nn) b1v[nn] = b1[w * 48 + nn * 16 + l16];
        #pragma unroll
        for (int m = 0; m < 4; ++m)
            #pragma unroll
            for (int nn = 0; nn < 3; ++nn) {
                const int col = w * 48 + nn * 16 + l16;
                #pragma unroll
                for (int reg = 0; reg < 4; ++reg) {
                    const int row = m * 16 + quad * 4 + reg;   // C: row=quad*4+reg, col=l16
                    Hs[row * 196 + col] = fmaxf(acc[m][nn][reg] + b1v[nn], 0.f);
                }
            }
    }
    __syncthreads();
    const int r = tid >> 2, qq = tid & 3;
    const int e0 = 2 * qq, e1 = e0 + 1;
    float s0 = b2s[e0], s1 = b2s[e1];
    const float* hrow = Hs + r * 196;
    const float* w0 = W2t + e0 * 196;
    const float* w1 = W2t + e1 * 196;
    #pragma unroll 8
    for (int c = 0; c < 192; c += 4) {
        float4 h4 = *(const float4*)(hrow + c);
        float4 a4 = *(const float4*)(w0 + c);
        float4 b4 = *(const float4*)(w1 + c);
        s0 = fmaf(h4.x, a4.x, fmaf(h4.y, a4.y, fmaf(h4.z, a4.z, fmaf(h4.w, a4.w, s0))));
        s1 = fmaf(h4.x, b4.x, fmaf(h4.y, b4.y, fmaf(h4.z, b4.z, fmaf(h4.w, b4.w, s1))));
    }
    out[(size_t)(row0 + r) * 8 + e0] = s0;
    out[(size_t)(row0 + r) * 8 + e1] = s1;
}

// ---------------------------------------------------------------------------
extern "C" void kernel_launch(void* const* d_in, const int* in_sizes, int n_in,
                              void* d_out, int out_size, void* d_ws, size_t ws_size,
                              hipStream_t stream) {
    const float* emb  = (const float*)d_in[0];
    const float* U    = (const float*)d_in[1];
    const float* R    = (const float*)d_in[2];
    const float* S    = (const float*)d_in[3];
    const float* W_tp = (const float*)d_in[4];
    const float* b_tp = (const float*)d_in[5];
    const float* W_q  = (const float*)d_in[6];
    const float* b_q  = (const float*)d_in[7];
    const float* W_k  = (const float*)d_in[8];
    const float* b_k  = (const float*)d_in[9];
    const float* W_v  = (const float*)d_in[10];
    const float* b_v  = (const float*)d_in[11];
    const float* W_ih = (const float*)d_in[12];
    const float* W_hh = (const float*)d_in[13];
    const float* b_ih = (const float*)d_in[14];
    const float* b_hh = (const float*)d_in[15];
    const float* W1   = (const float*)d_in[16];
    const float* b1   = (const float*)d_in[17];
    const float* W2   = (const float*)d_in[18];
    const float* b2   = (const float*)d_in[19];

    float* outp = (float*)d_out;

    // ws layout (bytes) — 25.4 MB (verified fits):
    //   proc  bf16 [32768,256] @ 0            16,777,216
    //   wrws  f32  [32768,2]   @ 16,777,216      262,144
    //   gout  bf16 [32768,128] @ 17,039,360    8,388,608
    //   cst   f32  [2336]      @ 25,427,968        9,344
    const size_t NEEDED = 25444352u;
    if (ws_size < NEEDED) {
        k_paint<<<(out_size + 255) / 256, 256, 0, stream>>>(outp, 3.0f, out_size);
        return;
    }

    char* ws = (char*)d_ws;
    unsigned short* proc = (unsigned short*)(ws);
    float*          wrws = (float*)(ws + 16777216u);
    unsigned short* gout = (unsigned short*)(ws + 17039360u);
    float*          cst  = (float*)(ws + 25427968u);

    k_prep<<<1, 512, 0, stream>>>(W_q, b_q, W_k, b_k, W_v, b_v, W_ih, b_ih, cst);
    k_proc<<<dim3(4, 256), 256, 0, stream>>>(emb, W_tp, b_tp, proc);
    k_attn<<<8192, 256, 0, stream>>>(proc, R, S, cst, wrws);
    k_gru <<<64, 256, 0, stream>>>(wrws, U, W_hh, b_hh, cst, gout);
    k_hid <<<512, 256, 0, stream>>>(proc, gout, W1, b1, W2, b2, outp);
}

// Round 9
// 524.814 us; speedup vs baseline: 1.0728x; 1.0728x over previous
//
#include <hip/hip_runtime.h>

// ---------------------------------------------------------------------------
// Dims: E=768 P=256 K=32 V=32 H=128 NE=8  B=16 M=4 T=512
// rows = 32768, sequences = 64.  All inputs f32; output f32.
// R14: k_gru reverted to R9-exact (R12's loop-head gout branch + split
// writeback + uvw prefetch cost +38us: inserted work on the barrier-to-
// ds_read critical path; conflicts 0->262K). Keep R12 k_proc (128x64 tile)
// and k_hid (MFMA + W2t vectorized epilogue): non-gru 269.6->264.0 us.
// k_gru floor analysis: ~96 MFMA/step/CU (~470cyc) structural; seq-batching
// refuted (R10), cross-block split impossible per-step.
// ---------------------------------------------------------------------------

typedef __attribute__((ext_vector_type(8))) short short8;
typedef __attribute__((ext_vector_type(4))) float f32x4;

__device__ __forceinline__ float bf2f(unsigned short u) {
    return __uint_as_float(((unsigned int)u) << 16);
}
__device__ __forceinline__ unsigned short f2bf(float f) {  // RNE
    unsigned int x = __float_as_uint(f);
    return (unsigned short)((x + 0x7FFFu + ((x >> 16) & 1u)) >> 16);
}
__device__ __forceinline__ float sigm(float x) { return 1.0f / (1.0f + __expf(-x)); }
__device__ __forceinline__ float tanh_fast(float x) {
    x = fminf(fmaxf(x, -15.0f), 15.0f);
    float e = __expf(-2.0f * x);
    return (1.0f - e) / (1.0f + e);
}
// lane^1 pair-sum via DPP quad_perm [1,0,3,2] (ctrl 0xB1) — pure VALU pipe.
__device__ __forceinline__ float dpp_xor1_add(float v) {
    int o = __builtin_amdgcn_update_dpp(0, __float_as_int(v), 0xB1, 0xF, 0xF, true);
    return v + __int_as_float(o);
}
// select c[sel] for sel in 0..3 (3 cndmask)
__device__ __forceinline__ float sel4(f32x4 c, int sel) {
    float t0 = (sel & 1) ? c[1] : c[0];
    float t1 = (sel & 1) ? c[3] : c[2];
    return (sel & 2) ? t1 : t0;
}

// const block layout (floats): wA@0 wB@256 wC@512 | cA,cB,cC@768 |
// wu@800 wA2@1184 wB2@1568 cc@1952  (end 2336)
#define CST_SC   768
#define CST_WU   800
#define CST_WA2  1184
#define CST_WB2  1568
#define CST_CC   1952

__global__ void k_paint(float* out, float val, int nmax) {
    int i = blockIdx.x * blockDim.x + threadIdx.x;
    if (i < nmax) out[i] = val;
}

// ---------------------------------------------------------------------------
// k_prep: weight fusions.  <<<1, 512>>>
// ---------------------------------------------------------------------------
__global__ void k_prep(const float* __restrict__ Wq,
                       const float* __restrict__ bq,
                       const float* __restrict__ Wk,
                       const float* __restrict__ bk,
                       const float* __restrict__ Wv,
                       const float* __restrict__ bv,
                       const float* __restrict__ Wih,
                       const float* __restrict__ bih,
                       float* __restrict__ cst)
{
    const int t = threadIdx.x;
    if (t < 256) {
        float a = 0.f, b = 0.f, c = 0.f;
        for (int k = 0; k < 32; ++k) {
            float w = Wq[t * 32 + k];
            a = fmaf(w, Wk[k], a);
            b = fmaf(w, Wk[32 + k], b);
            c = fmaf(w, bk[k], c);
        }
        cst[t] = a; cst[256 + t] = b; cst[512 + t] = c;
    }
    if (t == 0) {
        float ca = 0.f, cb = 0.f, cc = 0.f;
        for (int k = 0; k < 32; ++k) {
            float bqk = bq[k];
            ca = fmaf(bqk, Wk[k], ca);
            cb = fmaf(bqk, Wk[32 + k], cb);
            cc = fmaf(bqk, bk[k], cc);
        }
        cst[CST_SC + 0] = ca; cst[CST_SC + 1] = cb; cst[CST_SC + 2] = cc;
    }
    if (t < 384) {
        cst[CST_WU + t] = Wih[t * 33];
        float a2 = 0.f, b2 = 0.f, c2 = bih[t];
        for (int v = 0; v < 32; ++v) {
            float w = Wih[t * 33 + 1 + v];
            a2 = fmaf(w, Wv[v], a2);
            b2 = fmaf(w, Wv[32 + v], b2);
            c2 = fmaf(w, bv[v], c2);
        }
        cst[CST_WA2 + t] = a2; cst[CST_WB2 + t] = b2; cst[CST_CC + t] = c2;
    }
}

// ---------------------------------------------------------------------------
// k_proc (R12): proc = relu(emb @ W_tp + b_tp) -> bf16. MFMA 16x16x32.
// Tile 128x64, BK=32, block 256 (4 waves, 2x2 grid of 64x32), grid (4,256).
// ---------------------------------------------------------------------------
__global__ __launch_bounds__(256) void k_proc(
    const float* __restrict__ A,     // [32768,768] f32
    const float* __restrict__ Bw,    // [768,256]  f32
    const float* __restrict__ bias,  // [256] f32
    unsigned short* __restrict__ C)  // [32768,256] bf16
{
    __shared__ unsigned short A_s[128 * 40];  // [row][k] stride 40
    __shared__ unsigned short B_s[64 * 40];   // [col][k] stride 40 (transposed)
    const int t = threadIdx.x;
    const int row0 = blockIdx.y * 128;
    const int col0 = blockIdx.x * 64;
    const int lane = t & 63, wave = t >> 6;
    const int wr = wave >> 1, wc = wave & 1;      // 2x2 wave grid of 64x32
    const int quad = lane >> 4, l16 = lane & 15;

    f32x4 acc[4][2] = {};

    for (int k0 = 0; k0 < 768; k0 += 32) {
        {   // A tile: 128 rows x 32 k; thread: row=t>>1, 16 k each
            const int r = t >> 1, kq = (t & 1) * 16;
            const float* src = A + (size_t)(row0 + r) * 768 + k0 + kq;
            float4 v0 = *(const float4*)(src);
            float4 v1 = *(const float4*)(src + 4);
            float4 v2 = *(const float4*)(src + 8);
            float4 v3 = *(const float4*)(src + 12);
            short8 s0, s1;
            s0[0] = f2bf(v0.x); s0[1] = f2bf(v0.y); s0[2] = f2bf(v0.z); s0[3] = f2bf(v0.w);
            s0[4] = f2bf(v1.x); s0[5] = f2bf(v1.y); s0[6] = f2bf(v1.z); s0[7] = f2bf(v1.w);
            s1[0] = f2bf(v2.x); s1[1] = f2bf(v2.y); s1[2] = f2bf(v2.z); s1[3] = f2bf(v2.w);
            s1[4] = f2bf(v3.x); s1[5] = f2bf(v3.y); s1[6] = f2bf(v3.z); s1[7] = f2bf(v3.w);
            *(short8*)(A_s + r * 40 + kq) = s0;
            *(short8*)(A_s + r * 40 + kq + 8) = s1;
        }
        {   // B tile: 32 k x 64 cols, transposed into [col][k]
            const int k = t >> 3, nq = (t & 7) * 8;
            const float* src = Bw + (size_t)(k0 + k) * 256 + col0 + nq;
            float4 v0 = *(const float4*)(src);
            float4 v1 = *(const float4*)(src + 4);
            B_s[(nq + 0) * 40 + k] = f2bf(v0.x);
            B_s[(nq + 1) * 40 + k] = f2bf(v0.y);
            B_s[(nq + 2) * 40 + k] = f2bf(v0.z);
            B_s[(nq + 3) * 40 + k] = f2bf(v0.w);
            B_s[(nq + 4) * 40 + k] = f2bf(v1.x);
            B_s[(nq + 5) * 40 + k] = f2bf(v1.y);
            B_s[(nq + 6) * 40 + k] = f2bf(v1.z);
            B_s[(nq + 7) * 40 + k] = f2bf(v1.w);
        }
        __syncthreads();
        short8 af[4], bf[2];
        #pragma unroll
        for (int im = 0; im < 4; ++im)
            af[im] = *(const short8*)(A_s + (wr * 64 + im * 16 + l16) * 40 + quad * 8);
        #pragma unroll
        for (int in = 0; in < 2; ++in)
            bf[in] = *(const short8*)(B_s + (wc * 32 + in * 16 + l16) * 40 + quad * 8);
        #pragma unroll
        for (int im = 0; im < 4; ++im)
            #pragma unroll
            for (int in = 0; in < 2; ++in)
                acc[im][in] = __builtin_amdgcn_mfma_f32_16x16x32_bf16(
                    af[im], bf[in], acc[im][in], 0, 0, 0);
        __syncthreads();
    }
    float bias_v[2];
    #pragma unroll
    for (int in = 0; in < 2; ++in) bias_v[in] = bias[col0 + wc * 32 + in * 16 + l16];
    #pragma unroll
    for (int im = 0; im < 4; ++im)
        #pragma unroll
        for (int in = 0; in < 2; ++in) {
            const int c_g = col0 + wc * 32 + in * 16 + l16;
            #pragma unroll
            for (int reg = 0; reg < 4; ++reg) {
                const int r_g = row0 + wr * 64 + im * 16 + quad * 4 + reg;
                float v = fmaxf(acc[im][in][reg] + bias_v[in], 0.f);
                C[(size_t)r_g * 256 + c_g] = f2bf(v);
            }
        }
}

// ---------------------------------------------------------------------------
// k_attn: one WAVE per row; rank-1 attention reduced to (wr, ws) per row.
// ---------------------------------------------------------------------------
__global__ __launch_bounds__(256) void k_attn(
    const unsigned short* __restrict__ proc,  // bf16 internal
    const float* __restrict__ R,              // [16,4,4,512] f32
    const float* __restrict__ S,
    const float* __restrict__ cst,
    float* __restrict__ wrws)                 // [32768,2] f32
{
    __shared__ float wv_s[768];
    const int tid = threadIdx.x;
    for (int i = tid; i < 768; i += 256) wv_s[i] = cst[i];
    __syncthreads();

    const int lane = tid & 63, wave = tid >> 6;
    const int row = blockIdx.x * 4 + wave;
    const int t = row & 511, m = (row >> 9) & 3, b = row >> 11;
    const int p0 = lane * 4;

    ushort4 u = *(const ushort4*)(proc + (size_t)row * 256 + p0);
    float p0f = bf2f(u.x), p1f = bf2f(u.y), p2f = bf2f(u.z), p3f = bf2f(u.w);
    float dA = 0.f, dB = 0.f, dC = 0.f;
    dA = fmaf(p0f, wv_s[p0 + 0], dA); dB = fmaf(p0f, wv_s[256 + p0 + 0], dB); dC = fmaf(p0f, wv_s[512 + p0 + 0], dC);
    dA = fmaf(p1f, wv_s[p0 + 1], dA); dB = fmaf(p1f, wv_s[256 + p0 + 1], dB); dC = fmaf(p1f, wv_s[512 + p0 + 1], dC);
    dA = fmaf(p2f, wv_s[p0 + 2], dA); dB = fmaf(p2f, wv_s[256 + p0 + 2], dB); dC = fmaf(p2f, wv_s[512 + p0 + 2], dC);
    dA = fmaf(p3f, wv_s[p0 + 3], dA); dB = fmaf(p3f, wv_s[256 + p0 + 3], dB); dC = fmaf(p3f, wv_s[512 + p0 + 3], dC);
    #pragma unroll
    for (int mm = 1; mm < 64; mm <<= 1) {
        dA += __shfl_xor(dA, mm, 64);
        dB += __shfl_xor(dB, mm, 64);
        dC += __shfl_xor(dC, mm, 64);
    }
    if (lane == 0) {
        dA += cst[CST_SC + 0]; dB += cst[CST_SC + 1]; dC += cst[CST_SC + 2];
        const float scale = 0.17677669529663687f;  // 1/sqrt(32)
        float rr[4], ss[4], sc[4], mx = -1e30f;
        #pragma unroll
        for (int j = 0; j < 4; ++j) {
            const size_t idx = ((size_t)(b * 16 + m * 4 + j)) * 512 + t;
            rr[j] = R[idx]; ss[j] = S[idx];
            float v = (rr[j] * dA + ss[j] * dB + dC) * scale;
            if (j == m) v = -1e9f;
            sc[j] = v; mx = fmaxf(mx, v);
        }
        float w[4], se = 0.f;
        #pragma unroll
        for (int j = 0; j < 4; ++j) { w[j] = __expf(sc[j] - mx); se += w[j]; }
        const float inv = 1.0f / se;
        float wr = 0.f, wss = 0.f;
        #pragma unroll
        for (int j = 0; j < 4; ++j) { wr += w[j] * rr[j]; wss += w[j] * ss[j]; }
        float2 o; o.x = wr * inv; o.y = wss * inv;
        ((float2*)wrws)[row] = o;
    }
}

// ---------------------------------------------------------------------------
// k_gru (R9-exact, measured 261us twice): 64 blocks x 256 threads (4 waves).
// Wave w owns h[32w..32w+32) via 6 row-tiles. Lane (quad,l16): par=l16&1
// (hi/lo), sel=(l16>>1)&3, hh=(l16>>3)&1 -> eg = 32w + 16hh + 4quad + sel:
// ONE element per lane. 24 MFMA/wave/step, DPP xor1 hi+lo combine, 1 barrier.
// ---------------------------------------------------------------------------
__global__ __launch_bounds__(256) void k_gru(
    const float* __restrict__ wrws,
    const float* __restrict__ U,       // [32768] f32
    const float* __restrict__ Whh,     // [384,128] f32
    const float* __restrict__ bhh,     // [384] f32
    const float* __restrict__ cst,
    unsigned short* __restrict__ gout) // [32768,128] bf16
{
    __shared__ unsigned short hbuf[2][2][144];  // [buf][hi/lo][128 + 16 pad] bf16
    __shared__ float4 uvw_s[512];               // {u, wr, ws, 0} per t

    const int tid  = threadIdx.x;
    const int lane = tid & 63, w = tid >> 6;      // 4 waves
    const int l16  = lane & 15, quad = lane >> 4;
    const int n    = blockIdx.x;
    const int par  = l16 & 1;                     // B col parity: even=hi, odd=lo
    const int sel  = (l16 >> 1) & 3;              // C-fragment reg select
    const int hh   = (l16 >> 3) & 1;              // tile half select
    const int eg   = 32 * w + 16 * hh + quad * 4 + sel;  // this lane's h element
    const bool writer = (par == 0);

    // ---- A fragments: 6 row-tiles (3 gates x 2 halves), bf16 ----
    short8 afr[3][2][4];
    #pragma unroll
    for (int g3 = 0; g3 < 3; ++g3)
        #pragma unroll
        for (int h2 = 0; h2 < 2; ++h2) {
            const int row = g3 * 128 + 32 * w + 16 * h2 + l16;
            const float* rp = Whh + (size_t)row * 128 + quad * 8;
            #pragma unroll
            for (int kf = 0; kf < 4; ++kf) {
                float4 v0 = *(const float4*)(rp + kf * 32);
                float4 v1 = *(const float4*)(rp + kf * 32 + 4);
                short8 s;
                s[0] = f2bf(v0.x); s[1] = f2bf(v0.y); s[2] = f2bf(v0.z); s[3] = f2bf(v0.w);
                s[4] = f2bf(v1.x); s[5] = f2bf(v1.y); s[6] = f2bf(v1.z); s[7] = f2bf(v1.w);
                afr[g3][h2][kf] = s;
            }
        }

    // ---- per-lane gi constants for element eg (bhh folded for r,z) ----
    const float wu_r = cst[CST_WU  + eg], wu_z = cst[CST_WU  + 128 + eg], wu_n = cst[CST_WU  + 256 + eg];
    const float wa_r = cst[CST_WA2 + eg], wa_z = cst[CST_WA2 + 128 + eg], wa_n = cst[CST_WA2 + 256 + eg];
    const float wb_r = cst[CST_WB2 + eg], wb_z = cst[CST_WB2 + 128 + eg], wb_n = cst[CST_WB2 + 256 + eg];
    const float cc_r = cst[CST_CC  + eg] + bhh[eg];
    const float cc_z = cst[CST_CC  + 128 + eg] + bhh[128 + eg];
    const float cc_n = cst[CST_CC  + 256 + eg];
    const float bh_n = bhh[256 + eg];

    for (int i = tid; i < 512; i += 256) {   // per-t scalars, packed float4
        float u = U[(size_t)n * 512 + i];
        float2 w2 = ((const float2*)wrws)[(size_t)n * 512 + i];
        float4 p; p.x = u; p.y = w2.x; p.z = w2.y; p.w = 0.f;
        uvw_s[i] = p;
    }
    for (int i = tid; i < 288; i += 256) ((unsigned int*)hbuf)[i] = 0u;  // zero h bufs
    __syncthreads();

    float h_old = 0.f;
    const f32x4 ZZ = {0.f, 0.f, 0.f, 0.f};

    #pragma unroll 2
    for (int t = 0; t < 512; ++t) {
        const int cur = t & 1, nxt = cur ^ 1;

        // B fragments: h broadcast; col parity picks hi/lo plane
        const unsigned short* hb = &hbuf[cur][par][0];
        short8 bfr[4];
        #pragma unroll
        for (int kf = 0; kf < 4; ++kf)
            bfr[kf] = *(const short8*)(hb + kf * 32 + quad * 8);
        const float4 uvw = uvw_s[t];

        f32x4 c[6] = {ZZ, ZZ, ZZ, ZZ, ZZ, ZZ};   // c[2g+hh]: 6 chains of 4
        #pragma unroll
        for (int kf = 0; kf < 4; ++kf)
            #pragma unroll
            for (int j = 0; j < 6; ++j)
                c[j] = __builtin_amdgcn_mfma_f32_16x16x32_bf16(
                    afr[j >> 1][j & 1][kf], bfr[kf], c[j], 0, 0, 0);

        // gate g of eg = row (quad*4+sel), col l16 of tile c[2g+hh];
        // DPP xor-1 adds hi(par=0) + lo(par=1) partial products.
        float gh[3];
        #pragma unroll
        for (int g3 = 0; g3 < 3; ++g3) {
            const float v0 = sel4(c[2 * g3 + 0], sel);
            const float v1 = sel4(c[2 * g3 + 1], sel);
            gh[g3] = dpp_xor1_add(hh ? v1 : v0);
        }

        const float gir = fmaf(uvw.z, wb_r, fmaf(uvw.y, wa_r, fmaf(uvw.x, wu_r, cc_r)));
        const float giz = fmaf(uvw.z, wb_z, fmaf(uvw.y, wa_z, fmaf(uvw.x, wu_z, cc_z)));
        const float gin = fmaf(uvw.z, wb_n, fmaf(uvw.y, wa_n, fmaf(uvw.x, wu_n, cc_n)));
        const float r  = sigm(gir + gh[0]);
        const float z  = sigm(giz + gh[1]);
        const float nn = tanh_fast(fmaf(r, gh[2] + bh_n, gin));
        const float hn = fmaf(z, h_old - nn, nn);
        h_old = hn;

        if (writer) {   // par==0 lane writes its own element (hi + lo residual)
            const unsigned short hi16 = f2bf(hn);
            hbuf[nxt][0][eg] = hi16;
            hbuf[nxt][1][eg] = f2bf(hn - bf2f(hi16));
            gout[((size_t)n * 512 + t) * 128 + eg] = hi16;   // never drained in-loop
        }
        asm volatile("s_waitcnt lgkmcnt(0)" ::: "memory");
        __builtin_amdgcn_s_barrier();
        asm volatile("" ::: "memory");
        __builtin_amdgcn_sched_barrier(0x7);  // ALU may cross; DS/VMEM/MFMA pinned
    }
}

// ---------------------------------------------------------------------------
// k_hid (R12): hidden = relu([proc|gout]@W1 + b1) via MFMA (W1 bf16 hi+lo),
// logits = hidden@W2 + b2 with W2 TRANSPOSED in LDS [8][196] -> b128 reads.
// ---------------------------------------------------------------------------
__global__ __launch_bounds__(256) void k_hid(
    const unsigned short* __restrict__ proc,  // bf16 [32768,256]
    const unsigned short* __restrict__ gout,  // bf16 [32768,128]
    const float* __restrict__ W1,   // [384,192] f32
    const float* __restrict__ b1,   // [192] f32
    const float* __restrict__ W2,   // [192,8] f32
    const float* __restrict__ b2,   // [8] f32
    float* __restrict__ out)        // [32768,8] f32
{
    // LDS: K-loop  As[64][40] bf16 @0 (5120) | Bh[192][40] @5120 (15360) |
    //              Bl[192][40] @20480 (15360)            (K-loop total 35840)
    //      Epilog  Hs[64][196] f32 @0 (50176)  (reuses K-loop region)
    //      Always  W2t[8][196] f32 @50176 (6272) | b2s[8] @56448 (32)
    __shared__ __align__(16) unsigned char smem[56480];
    unsigned short* As = (unsigned short*)smem;            // stride 40
    unsigned short* Bh = (unsigned short*)(smem + 5120);   // stride 40
    unsigned short* Bl = (unsigned short*)(smem + 20480);  // stride 40
    float* Hs  = (float*)smem;                             // stride 196
    float* W2t = (float*)(smem + 50176);                   // [8][196]
    float* b2s = (float*)(smem + 56448);

    const int tid = threadIdx.x;
    const int row0 = blockIdx.x * 64;
    const int lane = tid & 63, w = tid >> 6;
    const int l16 = lane & 15, quad = lane >> 4;

    for (int i = tid; i < 1536; i += 256) {   // W2 [192,8] -> W2t [8][196]
        const int c = i >> 3, e = i & 7;
        W2t[e * 196 + c] = W2[i];
    }
    if (tid < 8) b2s[tid] = b2[tid];

    // staging maps: A: 8 bf16/thread; B: 2 k-rows x 12 cols (stride-16)/thread
    const int ar = tid >> 2, akq = (tid & 3) * 8;
    const int bk2 = (tid >> 4) * 2, bc0 = tid & 15;

    f32x4 acc[4][3] = {};

    for (int k0 = 0; k0 < 384; k0 += 32) {
        __syncthreads();   // previous iter's fragment reads complete
        {   // A tile: 64 rows x 32 k (bf16 direct copy from proc/gout)
            const int kk = k0 + akq;
            short8 v;
            if (kk < 256) v = *(const short8*)(proc + (size_t)(row0 + ar) * 256 + kk);
            else          v = *(const short8*)(gout + (size_t)(row0 + ar) * 128 + (kk - 256));
            *(short8*)(As + ar * 40 + akq) = v;
        }
        {   // B tile: W1[k0..k0+32][0..192] f32 -> [col][k] bf16 hi+lo planes
            const float* wrow0 = W1 + (size_t)(k0 + bk2) * 192;
            const float* wrow1 = wrow0 + 192;
            #pragma unroll
            for (int j = 0; j < 12; ++j) {
                const int c = bc0 + 16 * j;
                const float f0 = wrow0[c], f1 = wrow1[c];
                const unsigned short h0 = f2bf(f0), h1 = f2bf(f1);
                const unsigned short s0 = f2bf(f0 - bf2f(h0));
                const unsigned short s1 = f2bf(f1 - bf2f(h1));
                *(unsigned int*)(Bh + c * 40 + bk2) = (unsigned int)h0 | ((unsigned int)h1 << 16);
                *(unsigned int*)(Bl + c * 40 + bk2) = (unsigned int)s0 | ((unsigned int)s1 << 16);
            }
        }
        __syncthreads();
        short8 af[4], bh[3], bl[3];
        #pragma unroll
        for (int m = 0; m < 4; ++m)
            af[m] = *(const short8*)(As + (m * 16 + l16) * 40 + quad * 8);
        #pragma unroll
        for (int nn = 0; nn < 3; ++nn) {
            const int col = w * 48 + nn * 16 + l16;
            bh[nn] = *(const short8*)(Bh + col * 40 + quad * 8);
            bl[nn] = *(const short8*)(Bl + col * 40 + quad * 8);
        }
        #pragma unroll
        for (int m = 0; m < 4; ++m)
            #pragma unroll
            for (int nn = 0; nn < 3; ++nn) {
                acc[m][nn] = __builtin_amdgcn_mfma_f32_16x16x32_bf16(af[m], bh[nn], acc[m][nn], 0, 0, 0);
                acc[m][nn] = __builtin_amdgcn_mfma_f32_16x16x32_bf16(af[m], bl[nn], acc[m][nn], 0, 0, 0);
            }
    }
    __syncthreads();   // done with K-loop LDS before Hs overwrite
    {
        float b1v[3];
        #pragma unroll
        for (int nn = 0; nn < 3; ++nn) b1v[nn] = b1[w * 48 + nn * 16 + l16];
        #pragma unroll
        for (int m = 0; m < 4; ++m)
            #pragma unroll
            for (int nn = 0; nn < 3; ++nn) {
                const int col = w * 48 + nn * 16 + l16;
                #pragma unroll
                for (int reg = 0; reg < 4; ++reg) {
                    const int row = m * 16 + quad * 4 + reg;   // C: row=quad*4+reg, col=l16
                    Hs[row * 196 + col] = fmaxf(acc[m][nn][reg] + b1v[nn], 0.f);
                }
            }
    }
    __syncthreads();
    const int r = tid >> 2, qq = tid & 3;
    const int e0 = 2 * qq, e1 = e0 + 1;
    float s0 = b2s[e0], s1 = b2s[e1];
    const float* hrow = Hs + r * 196;
    const float* w0 = W2t + e0 * 196;
    const float* w1 = W2t + e1 * 196;
    #pragma unroll 8
    for (int c = 0; c < 192; c += 4) {
        float4 h4 = *(const float4*)(hrow + c);
        float4 a4 = *(const float4*)(w0 + c);
        float4 b4 = *(const float4*)(w1 + c);
        s0 = fmaf(h4.x, a4.x, fmaf(h4.y, a4.y, fmaf(h4.z, a4.z, fmaf(h4.w, a4.w, s0))));
        s1 = fmaf(h4.x, b4.x, fmaf(h4.y, b4.y, fmaf(h4.z, b4.z, fmaf(h4.w, b4.w, s1))));
    }
    out[(size_t)(row0 + r) * 8 + e0] = s0;
    out[(size_t)(row0 + r) * 8 + e1] = s1;
}

// ---------------------------------------------------------------------------
extern "C" void kernel_launch(void* const* d_in, const int* in_sizes, int n_in,
                              void* d_out, int out_size, void* d_ws, size_t ws_size,
                              hipStream_t stream) {
    const float* emb  = (const float*)d_in[0];
    const float* U    = (const float*)d_in[1];
    const float* R    = (const float*)d_in[2];
    const float* S    = (const float*)d_in[3];
    const float* W_tp = (const float*)d_in[4];
    const float* b_tp = (const float*)d_in[5];
    const float* W_q  = (const float*)d_in[6];
    const float* b_q  = (const float*)d_in[7];
    const float* W_k  = (const float*)d_in[8];
    const float* b_k  = (const float*)d_in[9];
    const float* W_v  = (const float*)d_in[10];
    const float* b_v  = (const float*)d_in[11];
    const float* W_ih = (const float*)d_in[12];
    const float* W_hh = (const float*)d_in[13];
    const float* b_ih = (const float*)d_in[14];
    const float* b_hh = (const float*)d_in[15];
    const float* W1   = (const float*)d_in[16];
    const float* b1   = (const float*)d_in[17];
    const float* W2   = (const float*)d_in[18];
    const float* b2   = (const float*)d_in[19];

    float* outp = (float*)d_out;

    // ws layout (bytes) — 25.4 MB (verified fits):
    //   proc  bf16 [32768,256] @ 0            16,777,216
    //   wrws  f32  [32768,2]   @ 16,777,216      262,144
    //   gout  bf16 [32768,128] @ 17,039,360    8,388,608
    //   cst   f32  [2336]      @ 25,427,968        9,344
    const size_t NEEDED = 25444352u;
    if (ws_size < NEEDED) {
        k_paint<<<(out_size + 255) / 256, 256, 0, stream>>>(outp, 3.0f, out_size);
        return;
    }

    char* ws = (char*)d_ws;
    unsigned short* proc = (unsigned short*)(ws);
    float*          wrws = (float*)(ws + 16777216u);
    unsigned short* gout = (unsigned short*)(ws + 17039360u);
    float*          cst  = (float*)(ws + 25427968u);

    k_prep<<<1, 512, 0, stream>>>(W_q, b_q, W_k, b_k, W_v, b_v, W_ih, b_ih, cst);
    k_proc<<<dim3(4, 256), 256, 0, stream>>>(emb, W_tp, b_tp, proc);
    k_attn<<<8192, 256, 0, stream>>>(proc, R, S, cst, wrws);
    k_gru <<<64, 256, 0, stream>>>(wrws, U, W_hh, b_hh, cst, gout);
    k_hid <<<512, 256, 0, stream>>>(proc, gout, W1, b1, W2, b2, outp);
}